// Round 2
// baseline (18463.376 us; speedup 1.0000x reference)
//
#include <hip/hip_runtime.h>
#include <hip/hip_bf16.h>

#define BATCH 2
#define SEQ   2048
#define HIDSZ 4096
#define NH    32
#define NKV   8
#define HD    128
#define HALFD 64
#define MROWS (BATCH*SEQ)   // 4096
#define KVDIM (NKV*HD)      // 1024

typedef __hip_bfloat16 bf16;

__device__ __forceinline__ float ldf(const bf16* p)  { return __bfloat162float(*p); }
__device__ __forceinline__ float ldf(const float* p) { return *p; }
__device__ __forceinline__ void  stf(bf16* p, float v)  { *p = __float2bfloat16(v); }
__device__ __forceinline__ void  stf(float* p, float v) { *p = v; }

// ---------------- GEMM: C[M,N] = A[M,K] @ B[K,N], row-major ----------------
// 128x128 tile, BK=8, 256 threads, 8x8 micro-tile per thread, fp32 accumulate.
template<typename TA, typename TB, typename TC>
__global__ __launch_bounds__(256)
void gemm_kernel(const TA* __restrict__ A, const TB* __restrict__ B,
                 TC* __restrict__ C, int M, int N, int K) {
    __shared__ float As[8][128];   // A^T tile
    __shared__ float Bs[8][128];
    int tid = threadIdx.x;
    int bx = blockIdx.x, by = blockIdx.y;
    int trow = (tid >> 4) << 3;    // 0..120
    int tcol = (tid & 15) << 3;    // 0..120

    float acc[8][8];
#pragma unroll
    for (int i = 0; i < 8; i++)
#pragma unroll
        for (int j = 0; j < 8; j++) acc[i][j] = 0.f;

    int ar = tid >> 1, ac = (tid & 1) << 2;   // A tile: 128 rows x 8 cols
    int br = tid >> 5, bc = (tid & 31) << 2;  // B tile: 8 rows x 128 cols
    const TA* Ap = A + (size_t)(by * 128 + ar) * K + ac;
    const TB* Bp = B + (size_t)br * N + bx * 128 + bc;

    for (int k0 = 0; k0 < K; k0 += 8) {
#pragma unroll
        for (int u = 0; u < 4; u++) As[ac + u][ar] = ldf(Ap + k0 + u);
#pragma unroll
        for (int u = 0; u < 4; u++) Bs[br][bc + u] = ldf(Bp + (size_t)k0 * N + u);
        __syncthreads();
#pragma unroll
        for (int kk = 0; kk < 8; kk++) {
            float a[8], b[8];
#pragma unroll
            for (int i = 0; i < 8; i++) a[i] = As[kk][trow + i];
#pragma unroll
            for (int j = 0; j < 8; j++) b[j] = Bs[kk][tcol + j];
#pragma unroll
            for (int i = 0; i < 8; i++)
#pragma unroll
                for (int j = 0; j < 8; j++)
                    acc[i][j] = fmaf(a[i], b[j], acc[i][j]);
        }
        __syncthreads();
    }
#pragma unroll
    for (int i = 0; i < 8; i++)
#pragma unroll
        for (int j = 0; j < 8; j++)
            stf(&C[(size_t)(by * 128 + trow + i) * N + bx * 128 + tcol + j], acc[i][j]);
}

// ---------------- RoPE (in place, tensor of shape [MROWS, heads*HD]) --------
template<typename T>
__global__ void rope_kernel(T* __restrict__ t, int heads) {
    int idx = blockIdx.x * blockDim.x + threadIdx.x;
    int i   = idx & (HALFD - 1);
    int r   = idx >> 6;
    int h   = r % heads;
    int row = r / heads;
    int pos = row & (SEQ - 1);
    // inv_freq = 10000^(-i/64) = exp(-i * ln(10000)/64)
    float inv_freq = expf(-(float)i * (9.210340371976184f / 64.0f));
    float ang = (float)pos * inv_freq;
    float s, c;
    sincosf(ang, &s, &c);
    size_t base = (size_t)row * ((size_t)heads * HD) + (size_t)h * HD;
    float x1 = ldf(&t[base + i]);
    float x2 = ldf(&t[base + i + HALFD]);
    stf(&t[base + i],         x1 * c - x2 * s);
    stf(&t[base + i + HALFD], x2 * c + x1 * s);
}

// ---------------- Attention: one block per (b, h, qpos) ---------------------
__global__ __launch_bounds__(256)
void attn_kernel(const bf16* __restrict__ q, const bf16* __restrict__ kk,
                 const bf16* __restrict__ vv, bf16* __restrict__ o) {
    int bid  = blockIdx.x;
    int qpos = bid & (SEQ - 1);
    int h    = (bid >> 11) & (NH - 1);
    int b    = bid >> 16;
    int kvh  = h >> 2;               // H/HKV = 4
    int tid  = threadIdx.x;

    __shared__ float qs[HD];
    __shared__ float p[SEQ];
    __shared__ float red[4];
    __shared__ float bcast;
    __shared__ float obuf[HD];

    const bf16* qrow = q + (size_t)(b * SEQ + qpos) * HIDSZ + h * HD;
    if (tid < HD) qs[tid] = __bfloat162float(qrow[tid]) * 0.08838834764831845f;
    __syncthreads();

    int n = qpos + 1;
    float lmax = -1e30f;
    for (int j = tid; j < n; j += 256) {
        const __hip_bfloat162* kr =
            (const __hip_bfloat162*)(kk + (size_t)(b * SEQ + j) * KVDIM + kvh * HD);
        float acc = 0.f;
#pragma unroll
        for (int d2 = 0; d2 < HALFD; d2++) {
            float2 kf = __bfloat1622float2(kr[d2]);
            acc = fmaf(qs[2 * d2],     kf.x, acc);
            acc = fmaf(qs[2 * d2 + 1], kf.y, acc);
        }
        p[j] = acc;
        lmax = fmaxf(lmax, acc);
    }
#pragma unroll
    for (int off = 32; off; off >>= 1) lmax = fmaxf(lmax, __shfl_down(lmax, off, 64));
    if ((tid & 63) == 0) red[tid >> 6] = lmax;
    __syncthreads();
    if (tid == 0) bcast = fmaxf(fmaxf(red[0], red[1]), fmaxf(red[2], red[3]));
    __syncthreads();
    float m = bcast;

    float lsum = 0.f;
    for (int j = tid; j < n; j += 256) {
        float e = __expf(p[j] - m);
        p[j] = e;
        lsum += e;
    }
#pragma unroll
    for (int off = 32; off; off >>= 1) lsum += __shfl_down(lsum, off, 64);
    __syncthreads();                       // everyone done with bcast read / p writes
    if ((tid & 63) == 0) red[tid >> 6] = lsum;
    __syncthreads();
    if (tid == 0) bcast = 1.f / (red[0] + red[1] + red[2] + red[3]);
    __syncthreads();
    float inv = bcast;

    // pass 2: O[d] = sum_j p[j] * V[j][d]; two threads per d
    int d    = tid & 127;
    int half = tid >> 7;
    float acc = 0.f;
    for (int j = half; j < n; j += 2)
        acc = fmaf(p[j], ldf(&vv[(size_t)(b * SEQ + j) * KVDIM + kvh * HD + d]), acc);
    if (half) obuf[d] = acc;
    __syncthreads();
    if (!half)
        stf(&o[(size_t)(b * SEQ + qpos) * HIDSZ + h * HD + d], (acc + obuf[d]) * inv);
}

// ---------------------------------------------------------------------------
extern "C" void kernel_launch(void* const* d_in, const int* in_sizes, int n_in,
                              void* d_out, int out_size, void* d_ws, size_t ws_size,
                              hipStream_t stream) {
    const float* x  = (const float*)d_in[0];
    const float* wq = (const float*)d_in[1];
    const float* wk = (const float*)d_in[2];
    const float* wv = (const float*)d_in[3];
    const float* wo = (const float*)d_in[4];
    float* out = (float*)d_out;

    // intermediates stored as bf16: q 32MB, k 8MB, v 8MB, ao 32MB = 80MB
    bf16* q  = (bf16*)d_ws;                            // 4096 x 4096
    bf16* k  = q + (size_t)MROWS * HIDSZ;              // 4096 x 1024
    bf16* v  = k + (size_t)MROWS * KVDIM;              // 4096 x 1024
    bf16* ao = v + (size_t)MROWS * KVDIM;              // 4096 x 4096

    // QKV projections (fp32 in, bf16 out, fp32 accumulate)
    gemm_kernel<float, float, bf16><<<dim3(HIDSZ / 128, MROWS / 128), 256, 0, stream>>>(
        x, wq, q, MROWS, HIDSZ, HIDSZ);
    gemm_kernel<float, float, bf16><<<dim3(KVDIM / 128, MROWS / 128), 256, 0, stream>>>(
        x, wk, k, MROWS, KVDIM, HIDSZ);
    gemm_kernel<float, float, bf16><<<dim3(KVDIM / 128, MROWS / 128), 256, 0, stream>>>(
        x, wv, v, MROWS, KVDIM, HIDSZ);

    // RoPE on q (32 heads) and k (8 heads)
    rope_kernel<bf16><<<(MROWS * NH * HALFD) / 256, 256, 0, stream>>>(q, NH);
    rope_kernel<bf16><<<(MROWS * NKV * HALFD) / 256, 256, 0, stream>>>(k, NKV);

    // causal GQA attention
    attn_kernel<<<BATCH * NH * SEQ, 256, 0, stream>>>(q, k, v, ao);

    // output projection (bf16 in, fp32 out)
    gemm_kernel<bf16, float, float><<<dim3(HIDSZ / 128, MROWS / 128), 256, 0, stream>>>(
        ao, wo, out, MROWS, HIDSZ, HIDSZ);
}

// Round 3
// 5557.036 us; speedup vs baseline: 3.3225x; 3.3225x over previous
//
#include <hip/hip_runtime.h>
#include <hip/hip_bf16.h>

#define BATCH 2
#define SEQ   2048
#define HIDSZ 4096
#define NH    32
#define NKV   8
#define HD    128
#define HALFD 64
#define MROWS (BATCH*SEQ)   // 4096
#define KVDIM (NKV*HD)      // 1024

typedef __hip_bfloat16 bf16;
typedef __attribute__((ext_vector_type(8))) short short8;
typedef __attribute__((ext_vector_type(4))) float floatx4;

__device__ __forceinline__ float ldf(const bf16* p)  { return __bfloat162float(*p); }
__device__ __forceinline__ float ldf(const float* p) { return *p; }
__device__ __forceinline__ void  stf(bf16* p, float v)  { *p = __float2bfloat16(v); }
__device__ __forceinline__ void  stf(float* p, float v) { *p = v; }
__device__ __forceinline__ short bf16bits(float v) {
    __hip_bfloat16 hb = __float2bfloat16(v);
    return *(short*)&hb;
}

// ---------------- GEMM: C[M,N] = A[M,K] @ B[K,N], row-major ----------------
// 128x128 tile, BK=8, 256 threads, 8x8 micro-tile per thread, fp32 accumulate.
template<typename TA, typename TB, typename TC>
__global__ __launch_bounds__(256)
void gemm_kernel(const TA* __restrict__ A, const TB* __restrict__ B,
                 TC* __restrict__ C, int M, int N, int K) {
    __shared__ float As[8][128];   // A^T tile
    __shared__ float Bs[8][128];
    int tid = threadIdx.x;
    int bx = blockIdx.x, by = blockIdx.y;
    int trow = (tid >> 4) << 3;
    int tcol = (tid & 15) << 3;

    float acc[8][8];
#pragma unroll
    for (int i = 0; i < 8; i++)
#pragma unroll
        for (int j = 0; j < 8; j++) acc[i][j] = 0.f;

    int ar = tid >> 1, ac = (tid & 1) << 2;
    int br = tid >> 5, bc = (tid & 31) << 2;
    const TA* Ap = A + (size_t)(by * 128 + ar) * K + ac;
    const TB* Bp = B + (size_t)br * N + bx * 128 + bc;

    for (int k0 = 0; k0 < K; k0 += 8) {
#pragma unroll
        for (int u = 0; u < 4; u++) As[ac + u][ar] = ldf(Ap + k0 + u);
#pragma unroll
        for (int u = 0; u < 4; u++) Bs[br][bc + u] = ldf(Bp + (size_t)k0 * N + u);
        __syncthreads();
#pragma unroll
        for (int kk = 0; kk < 8; kk++) {
            float a[8], b[8];
#pragma unroll
            for (int i = 0; i < 8; i++) a[i] = As[kk][trow + i];
#pragma unroll
            for (int j = 0; j < 8; j++) b[j] = Bs[kk][tcol + j];
#pragma unroll
            for (int i = 0; i < 8; i++)
#pragma unroll
                for (int j = 0; j < 8; j++)
                    acc[i][j] = fmaf(a[i], b[j], acc[i][j]);
        }
        __syncthreads();
    }
#pragma unroll
    for (int i = 0; i < 8; i++)
#pragma unroll
        for (int j = 0; j < 8; j++)
            stf(&C[(size_t)(by * 128 + trow + i) * N + bx * 128 + tcol + j], acc[i][j]);
}

// ---------------- RoPE (in place, tensor of shape [MROWS, heads*HD]) --------
template<typename T>
__global__ void rope_kernel(T* __restrict__ t, int heads) {
    int idx = blockIdx.x * blockDim.x + threadIdx.x;
    int i   = idx & (HALFD - 1);
    int r   = idx >> 6;
    int h   = r % heads;
    int row = r / heads;
    int pos = row & (SEQ - 1);
    float inv_freq = expf(-(float)i * (9.210340371976184f / 64.0f));
    float ang = (float)pos * inv_freq;
    float s, c;
    sincosf(ang, &s, &c);
    size_t base = (size_t)row * ((size_t)heads * HD) + (size_t)h * HD;
    float x1 = ldf(&t[base + i]);
    float x2 = ldf(&t[base + i + HALFD]);
    stf(&t[base + i],         x1 * c - x2 * s);
    stf(&t[base + i + HALFD], x2 * c + x1 * s);
}

// ---------------- V transpose: v[B*SEQ][KVDIM] -> vt[B][NKV][HD][SEQ] -------
__global__ __launch_bounds__(256)
void transpose_v_kernel(const bf16* __restrict__ v, bf16* __restrict__ vt) {
    __shared__ short tile[32][33];
    int ts = blockIdx.x * 32;          // seq tile
    int td = blockIdx.y * 32;          // d tile within head
    int bk = blockIdx.z;               // b*NKV + kvh
    int b = bk >> 3, kvh = bk & 7;
    int tx = threadIdx.x & 31, ty = threadIdx.x >> 5;
    const short* vp = (const short*)v;
    short* vtp = (short*)vt;
#pragma unroll
    for (int i = 0; i < 4; i++) {
        int s = ts + ty + i * 8;
        tile[ty + i * 8][tx] = vp[(size_t)(b * SEQ + s) * KVDIM + kvh * HD + td + tx];
    }
    __syncthreads();
#pragma unroll
    for (int i = 0; i < 4; i++) {
        int d = td + ty + i * 8;
        vtp[((size_t)(b * NKV + kvh) * HD + d) * SEQ + ts + tx] = tile[tx][ty + i * 8];
    }
}

// ---------------- Flash attention: block = (b, h, 64-row q tile) ------------
// 4 waves; wave w owns q rows [q0+16w, q0+16w+15]. mfma_f32_16x16x32_bf16.
// A-frag: A[m=lane&15][k=quad*8+j]; B-frag: B[k=quad*8+j][n=lane&15];
// C/D: row=quad*4+reg, col=lane&15.  (m89/m91/m120-verified layouts)
__global__ __launch_bounds__(256)
void flash_attn_kernel(const bf16* __restrict__ q, const bf16* __restrict__ k,
                       const bf16* __restrict__ vt, bf16* __restrict__ ao) {
    int qt = blockIdx.x, h = blockIdx.y, b = blockIdx.z;
    int kvh = h >> 2;
    int tid = threadIdx.x;
    int wave = tid >> 6, lane = tid & 63;
    int col = lane & 15, quad = lane >> 4;
    int q0 = qt * 64;

    __shared__ short lds_p[4][16][64];   // per-wave P staging (C->A layout)

    // Q frags: qf[ks] = Q[q0+16w+col][h*HD + ks*32 + quad*8 .. +7]
    short8 qf[4];
    {
        const short* qbase = (const short*)q +
            (size_t)(b * SEQ + q0 + wave * 16 + col) * HIDSZ + h * HD + quad * 8;
#pragma unroll
        for (int ks = 0; ks < 4; ks++)
            qf[ks] = *(const short8*)(qbase + ks * 32);
    }

    float m_i[4], l_i[4];
#pragma unroll
    for (int r = 0; r < 4; r++) { m_i[r] = -1e30f; l_i[r] = 0.f; }
    floatx4 O[8];
#pragma unroll
    for (int n = 0; n < 8; n++)
#pragma unroll
        for (int r = 0; r < 4; r++) O[n][r] = 0.f;

    const short* kbase  = (const short*)k + (size_t)(b * SEQ) * KVDIM + kvh * HD + quad * 8;
    const short* vtbase = (const short*)vt + ((size_t)(b * NKV + kvh) * HD + col) * SEQ + quad * 8;
    const float scale = 0.08838834764831845f;   // 1/sqrt(128)

    for (int j0 = 0; j0 <= q0; j0 += 64) {
        // ---- S[16 x 64] = Q Kt (4 n-tiles of 16) ----
        floatx4 S[4];
#pragma unroll
        for (int nt = 0; nt < 4; nt++) {
            floatx4 acc;
#pragma unroll
            for (int r = 0; r < 4; r++) acc[r] = 0.f;
            const short* kp = kbase + (size_t)(j0 + nt * 16 + col) * KVDIM;
#pragma unroll
            for (int ks = 0; ks < 4; ks++)
                acc = __builtin_amdgcn_mfma_f32_16x16x32_bf16(
                          qf[ks], *(const short8*)(kp + ks * 32), acc, 0, 0, 0);
#pragma unroll
            for (int r = 0; r < 4; r++) S[nt][r] = acc[r] * scale;
        }
        // ---- causal mask (diagonal tile only) ----
        if (j0 == q0) {
            int rowb = wave * 16 + quad * 4;
#pragma unroll
            for (int nt = 0; nt < 4; nt++)
#pragma unroll
                for (int r = 0; r < 4; r++)
                    if (nt * 16 + col > rowb + r) S[nt][r] = -1e30f;
        }
        // ---- online softmax over this tile ----
        float mn[4], alpha[4];
#pragma unroll
        for (int r = 0; r < 4; r++) {
            float mx = fmaxf(fmaxf(S[0][r], S[1][r]), fmaxf(S[2][r], S[3][r]));
#pragma unroll
            for (int d = 8; d >= 1; d >>= 1) mx = fmaxf(mx, __shfl_xor(mx, d, 64));
            mn[r] = fmaxf(m_i[r], mx);
            alpha[r] = __expf(m_i[r] - mn[r]);
            m_i[r] = mn[r];
        }
#pragma unroll
        for (int nt = 0; nt < 4; nt++)
#pragma unroll
            for (int r = 0; r < 4; r++) S[nt][r] = __expf(S[nt][r] - mn[r]);
#pragma unroll
        for (int r = 0; r < 4; r++) {
            float s = (S[0][r] + S[1][r]) + (S[2][r] + S[3][r]);
#pragma unroll
            for (int d = 8; d >= 1; d >>= 1) s += __shfl_xor(s, d, 64);
            l_i[r] = l_i[r] * alpha[r] + s;
        }
#pragma unroll
        for (int n = 0; n < 8; n++)
#pragma unroll
            for (int r = 0; r < 4; r++) O[n][r] *= alpha[r];
        // ---- P: C-layout regs -> LDS -> A-layout frags ----
#pragma unroll
        for (int nt = 0; nt < 4; nt++)
#pragma unroll
            for (int r = 0; r < 4; r++)
                lds_p[wave][quad * 4 + r][nt * 16 + col] = bf16bits(S[nt][r]);
        __syncthreads();
        short8 pf[2];
#pragma unroll
        for (int ks2 = 0; ks2 < 2; ks2++)
            pf[ks2] = *(const short8*)&lds_p[wave][col][ks2 * 32 + quad * 8];
        // ---- O += P V (8 d-tiles of 16) ----
#pragma unroll
        for (int n = 0; n < 8; n++) {
            const short* vp = vtbase + (size_t)(n * 16) * SEQ + j0;
#pragma unroll
            for (int ks2 = 0; ks2 < 2; ks2++)
                O[n] = __builtin_amdgcn_mfma_f32_16x16x32_bf16(
                           pf[ks2], *(const short8*)(vp + ks2 * 32), O[n], 0, 0, 0);
        }
        __syncthreads();
    }

    // ---- epilogue: normalize, store (C layout) ----
#pragma unroll
    for (int r = 0; r < 4; r++) l_i[r] = 1.f / l_i[r];
    int orow = q0 + wave * 16 + quad * 4;
#pragma unroll
    for (int n = 0; n < 8; n++)
#pragma unroll
        for (int r = 0; r < 4; r++)
            ao[(size_t)(b * SEQ + orow + r) * HIDSZ + h * HD + n * 16 + col] =
                __float2bfloat16(O[n][r] * l_i[r]);
}

// ---------------------------------------------------------------------------
extern "C" void kernel_launch(void* const* d_in, const int* in_sizes, int n_in,
                              void* d_out, int out_size, void* d_ws, size_t ws_size,
                              hipStream_t stream) {
    const float* x  = (const float*)d_in[0];
    const float* wq = (const float*)d_in[1];
    const float* wk = (const float*)d_in[2];
    const float* wv = (const float*)d_in[3];
    const float* wo = (const float*)d_in[4];
    float* out = (float*)d_out;

    // ws: q 32MB | k 8MB | v 8MB | ao 32MB | vt 16MB  = 96MB bf16
    bf16* q  = (bf16*)d_ws;                            // [4096][4096]
    bf16* k  = q + (size_t)MROWS * HIDSZ;              // [4096][1024]
    bf16* v  = k + (size_t)MROWS * KVDIM;              // [4096][1024]
    bf16* ao = v + (size_t)MROWS * KVDIM;              // [4096][4096]
    bf16* vt = ao + (size_t)MROWS * HIDSZ;             // [2][8][128][2048]

    gemm_kernel<float, float, bf16><<<dim3(HIDSZ / 128, MROWS / 128), 256, 0, stream>>>(
        x, wq, q, MROWS, HIDSZ, HIDSZ);
    gemm_kernel<float, float, bf16><<<dim3(KVDIM / 128, MROWS / 128), 256, 0, stream>>>(
        x, wk, k, MROWS, KVDIM, HIDSZ);
    gemm_kernel<float, float, bf16><<<dim3(KVDIM / 128, MROWS / 128), 256, 0, stream>>>(
        x, wv, v, MROWS, KVDIM, HIDSZ);

    rope_kernel<bf16><<<(MROWS * NH * HALFD) / 256, 256, 0, stream>>>(q, NH);
    rope_kernel<bf16><<<(MROWS * NKV * HALFD) / 256, 256, 0, stream>>>(k, NKV);

    transpose_v_kernel<<<dim3(SEQ / 32, HD / 32, BATCH * NKV), 256, 0, stream>>>(v, vt);

    flash_attn_kernel<<<dim3(SEQ / 64, NH, BATCH), 256, 0, stream>>>(q, k, vt, ao);

    gemm_kernel<bf16, float, float><<<dim3(HIDSZ / 128, MROWS / 128), 256, 0, stream>>>(
        ao, wo, out, MROWS, HIDSZ, HIDSZ);
}